// Round 10
// baseline (237.245 us; speedup 1.0000x reference)
//
#include <hip/hip_runtime.h>
#include <math.h>

#define Bb 8
#define Nn 512
#define Mm 64
#define Dd 128
#define Hh 64
#define NEG_BIG (-1.0e30f)

typedef __bf16 bf16x8 __attribute__((ext_vector_type(8)));
typedef float  f32x4  __attribute__((ext_vector_type(4)));

// ws byte offsets (16B-aligned)
#define WS_WEB   0u          // 16384 B  bf16 We B-frags, frag-linear [16 frag][64 lane][8]
#define WS_W2B   16384u      // 8192 B   bf16 W2 B-frags, frag-linear [8 frag][64 lane][8]
#define WS_CWSF  24576u      // 131072 B fp32 CwsF[b][w][t][lane][r] (b1 folded, frag-swizzled)
#define WS_AOP   155648u     // 1048576 B fp32 Aop[b*N+n][h]
#define WS_SCORE 1204224u    // 1048576 B fp32 scores[b*N+n][m]
#define WS_PART  2252800u    // 32768 B  fp32 (max,sumexp) per block [4096][2]

// ---------- prep: weight B-frags + projections (CwsF frag-swizzled) ----------
__global__ __launch_bounds__(256) void prep_kernel(
    const float* __restrict__ W1, const float* __restrict__ W2,
    const float* __restrict__ op_emb, const float* __restrict__ machine_emb,
    const float* __restrict__ b1, char* __restrict__ ws)
{
    if (blockIdx.x < 48) {               // weight fragment prep
        __bf16* WeB = (__bf16*)(ws + WS_WEB);
        __bf16* W2B = (__bf16*)(ws + WS_W2B);
        int idx = blockIdx.x * 256 + threadIdx.x;
        if (idx < 8192) {                // We: 16 frags (t 0..3, ks 0..3)
            int fid = idx >> 9, rem = idx & 511;
            int lane = rem >> 3, j = rem & 7;
            int t = fid >> 2, ks = fid & 3;
            int q = lane >> 4, ln = lane & 15;
            int d = ks * 32 + q * 8 + j;
            int h = t * 16 + ln;
            WeB[idx] = (__bf16)W1[(size_t)(2 * Dd + d) * Hh + h];
        } else {                         // W2: 8 frags (t 0..3, ks 0..1)
            int i2 = idx - 8192;
            int fid = i2 >> 9, rem = i2 & 511;
            int lane = rem >> 3, j = rem & 7;
            int t = fid >> 1, ks = fid & 1;
            int q = lane >> 4, ln = lane & 15;
            int k = ks * 32 + q * 8 + j;
            int h = t * 16 + ln;
            W2B[i2] = (__bf16)W2[(size_t)k * Hh + h];
        }
        return;
    }
    // projections: 1152 blocks x 4 rows (B*M + B*N = 4608 rows of 64)
    float* CwsF = (float*)(ws + WS_CWSF);
    float* Aop  = (float*)(ws + WS_AOP);
    const int bid = (blockIdx.x - 48) * 4 + (threadIdx.x >> 6);
    const int h = threadIdx.x & 63;
    if (bid < Bb * Mm) {
        const float* mg = machine_emb + (size_t)bid * Dd;
        const float* Wm = W1 + (size_t)Dd * Hh;
        float acc = b1[h];
#pragma unroll 8
        for (int d = 0; d < Dd; ++d) acc = fmaf(mg[d], Wm[d * Hh + h], acc);
        // scatter into fragment order: [b][w][t][lane=q*16+ln][r]
        int b = bid >> 6, m = bid & 63;
        int wq = m >> 4, q = (m >> 2) & 3, r = m & 3;
        int t = h >> 4, ln = h & 15;
        CwsF[((((b * 4 + wq) * 4 + t) * 64) + (q * 16 + ln)) * 4 + r] = acc;
    } else {
        const int bn = bid - Bb * Mm;
        const float* og = op_emb + (size_t)bn * Dd;
        float acc = 0.f;
#pragma unroll 8
        for (int d = 0; d < Dd; ++d) acc = fmaf(og[d], W1[d * Hh + h], acc);
        Aop[(size_t)bn * Hh + h] = acc;
    }
}

// ---------- main: one n per block, zero pipelining, max independent blocks ----------
__global__ __launch_bounds__(256, 2) void main_kernel(
    const float* __restrict__ edge_emb, const int* __restrict__ mask,
    const float* __restrict__ b2, const float* __restrict__ W3,
    const float* __restrict__ b3, char* __restrict__ ws)
{
    __shared__ __bf16 sH1[Mm * 72];     // 9216 B, wave-private row tiles
    __shared__ float  sRed[8];

    float* scores = (float*)(ws + WS_SCORE);
    float* part   = (float*)(ws + WS_PART);

    const int tid  = threadIdx.x;
    const int lane = tid & 63;
    const int w    = tid >> 6;
    const int q    = lane >> 4;
    const int ln   = lane & 15;
    const int bn   = blockIdx.x;
    const int b    = bn >> 9;

    // ---- all global loads up-front, fully independent ----
    // edge A-frag raw data: 8 x float4 per lane
    const float* Eg = edge_emb + (size_t)bn * (Mm * Dd) + (w * 16 + ln) * Dd + q * 8;
    float4 raw[8];
#pragma unroll
    for (int ks = 0; ks < 4; ++ks) {
        raw[2 * ks]     = *(const float4*)&Eg[ks * 32];
        raw[2 * ks + 1] = *(const float4*)&Eg[ks * 32 + 4];
    }
    // weights (frag-linear, lane*16B; L2-resident)
    bf16x8 weF[16], w2F[8];
    {
        const bf16x8* WeB = (const bf16x8*)(ws + WS_WEB);
        const bf16x8* W2B = (const bf16x8*)(ws + WS_W2B);
#pragma unroll
        for (int f = 0; f < 16; ++f) weF[f] = WeB[f * 64 + lane];
#pragma unroll
        for (int f = 0; f < 8; ++f)  w2F[f] = W2B[f * 64 + lane];
    }
    // Cws tile (frag-swizzled), Aop, mask, small vectors
    f32x4 cv[4];
    {
        const f32x4* CwsF = (const f32x4*)(ws + WS_CWSF) + (size_t)b * 1024;
#pragma unroll
        for (int t = 0; t < 4; ++t) cv[t] = CwsF[(w * 4 + t) * 64 + lane];
    }
    const float* Aop = (const float*)(ws + WS_AOP) + (size_t)bn * Hh;
    float aopv[4];
#pragma unroll
    for (int t = 0; t < 4; ++t) aopv[t] = Aop[t * 16 + ln];
    const int4 mk = *(const int4*)&mask[(size_t)bn * Mm + w * 16 + q * 4];
    float b2v[4], w3v[4];
#pragma unroll
    for (int t = 0; t < 4; ++t) { b2v[t] = b2[t * 16 + ln]; w3v[t] = W3[t * 16 + ln]; }
    const float bias3 = b3[0];

    // ---- convert to bf16 A-frags ----
    bf16x8 af[4];
#pragma unroll
    for (int ks = 0; ks < 4; ++ks) {
        float4 lo = raw[2 * ks], hi = raw[2 * ks + 1];
        bf16x8 a;
        a[0] = (__bf16)lo.x; a[1] = (__bf16)lo.y; a[2] = (__bf16)lo.z; a[3] = (__bf16)lo.w;
        a[4] = (__bf16)hi.x; a[5] = (__bf16)hi.y; a[6] = (__bf16)hi.z; a[7] = (__bf16)hi.w;
        af[ks] = a;
    }

    // ---- GEMM1: D = edge . We + (Aop + Cws) ----
    f32x4 acc[4];
#pragma unroll
    for (int t = 0; t < 4; ++t) {
        acc[t][0] = cv[t][0] + aopv[t]; acc[t][1] = cv[t][1] + aopv[t];
        acc[t][2] = cv[t][2] + aopv[t]; acc[t][3] = cv[t][3] + aopv[t];
    }
#pragma unroll
    for (int t = 0; t < 4; ++t)
#pragma unroll
        for (int ks = 0; ks < 4; ++ks)
            acc[t] = __builtin_amdgcn_mfma_f32_16x16x32_bf16(af[ks], weF[t * 4 + ks], acc[t], 0, 0, 0);

    // ---- epilogue 1: relu -> sH1 (wave-private rows, no barrier) ----
#pragma unroll
    for (int t = 0; t < 4; ++t)
#pragma unroll
        for (int r = 0; r < 4; ++r)
            sH1[(w * 16 + q * 4 + r) * 72 + t * 16 + ln] = (__bf16)fmaxf(acc[t][r], 0.f);

    // ---- GEMM2 ----
    bf16x8 a2[2];
#pragma unroll
    for (int ks = 0; ks < 2; ++ks)
        a2[ks] = *(const bf16x8*)&sH1[(w * 16 + ln) * 72 + ks * 32 + q * 8];
    f32x4 c2[4];
#pragma unroll
    for (int t = 0; t < 4; ++t) c2[t] = (f32x4){0.f, 0.f, 0.f, 0.f};
#pragma unroll
    for (int t = 0; t < 4; ++t)
#pragma unroll
        for (int ks = 0; ks < 2; ++ks)
            c2[t] = __builtin_amdgcn_mfma_f32_16x16x32_bf16(a2[ks], w2F[t * 2 + ks], c2[t], 0, 0, 0);

    // ---- epilogue 2: masked scores + per-block softmax partial ----
    float p[4] = {0.f, 0.f, 0.f, 0.f};
#pragma unroll
    for (int t = 0; t < 4; ++t)
#pragma unroll
        for (int r = 0; r < 4; ++r)
            p[r] += fmaxf(c2[t][r] + b2v[t], 0.f) * w3v[t];
#pragma unroll
    for (int r = 0; r < 4; ++r) {
        p[r] += __shfl_xor(p[r], 1, 64);
        p[r] += __shfl_xor(p[r], 2, 64);
        p[r] += __shfl_xor(p[r], 4, 64);
        p[r] += __shfl_xor(p[r], 8, 64);
    }
    float m_loc = NEG_BIG, l_loc = 0.f;
    const int m0 = w * 16 + q * 4;
    {
        const int mkv[4] = {mk.x, mk.y, mk.z, mk.w};
        float vv[4];
#pragma unroll
        for (int r = 0; r < 4; ++r) {
            float v = p[r] + bias3;
            vv[r] = mkv[r] ? v : NEG_BIG;
            if (mkv[r]) {
                float mn = fmaxf(m_loc, v);
                l_loc = l_loc * expf(m_loc - mn) + expf(v - mn);
                m_loc = mn;
            }
        }
        if (ln == 0) {
            float4 o; o.x = vv[0]; o.y = vv[1]; o.z = vv[2]; o.w = vv[3];
            *(float4*)&scores[(size_t)bn * Mm + m0] = o;
        }
    }
    // combine q-groups (all ln copies identical), then waves
#pragma unroll
    for (int off = 16; off <= 32; off <<= 1) {
        float mo = __shfl_xor(m_loc, off, 64);
        float lo2 = __shfl_xor(l_loc, off, 64);
        float mn = fmaxf(m_loc, mo);
        l_loc = l_loc * expf(m_loc - mn) + lo2 * expf(mo - mn);
        m_loc = mn;
    }
    if (lane == 0) { sRed[w * 2] = m_loc; sRed[w * 2 + 1] = l_loc; }
    __syncthreads();
    if (tid == 0) {
        float gm = sRed[0], gl = sRed[1];
#pragma unroll
        for (int k = 1; k < 4; ++k) {
            float mo = sRed[k * 2], lo2 = sRed[k * 2 + 1];
            float mn = fmaxf(gm, mo);
            gl = gl * expf(gm - mn) + lo2 * expf(mo - mn);
            gm = mn;
        }
        float2 o; o.x = gm; o.y = gl;
        *(float2*)&part[bn * 2] = o;
    }
}

// ---------- log-softmax: combine 512 partials per batch inline, apply ----------
__global__ __launch_bounds__(256) void lsm_apply_kernel(
    const char* __restrict__ ws, float* __restrict__ out)
{
    const float4* s4 = (const float4*)(ws + WS_SCORE);
    const float* part = (const float*)(ws + WS_PART);
    __shared__ float sComb[8];
    __shared__ float sCC;
    const int tid = threadIdx.x;
    const int b = blockIdx.x >> 5;       // 32 blocks per batch; 512 partials each
    {
        float4 v = *(const float4*)&part[(size_t)b * 1024 + tid * 4]; // 2 partials
        float mn = fmaxf(v.x, v.z);
        float m_loc = mn;
        float l_loc = v.y * expf(v.x - mn) + v.w * expf(v.z - mn);
#pragma unroll
        for (int off = 1; off < 64; off <<= 1) {
            float mo = __shfl_xor(m_loc, off, 64);
            float lo2 = __shfl_xor(l_loc, off, 64);
            float nm = fmaxf(m_loc, mo);
            l_loc = l_loc * expf(m_loc - nm) + lo2 * expf(mo - nm);
            m_loc = nm;
        }
        if ((tid & 63) == 0) { sComb[(tid >> 6) * 2] = m_loc; sComb[(tid >> 6) * 2 + 1] = l_loc; }
    }
    __syncthreads();
    if (tid == 0) {
        float gm = sComb[0], gl = sComb[1];
#pragma unroll
        for (int k = 1; k < 4; ++k) {
            float mo = sComb[k * 2], lo2 = sComb[k * 2 + 1];
            float mn = fmaxf(gm, mo);
            gl = gl * expf(gm - mn) + lo2 * expf(mo - mn);
            gm = mn;
        }
        sCC = gm + logf(gl);
    }
    __syncthreads();
    const float c = sCC;
    const int i = blockIdx.x * 256 + tid;    // 65536 float4s
    float4 v = s4[i];
    v.x -= c; v.y -= c; v.z -= c; v.w -= c;
    ((float4*)out)[i] = v;
}

extern "C" void kernel_launch(void* const* d_in, const int* in_sizes, int n_in,
                              void* d_out, int out_size, void* d_ws, size_t ws_size,
                              hipStream_t stream)
{
    const float* op_emb      = (const float*)d_in[0];
    const float* machine_emb = (const float*)d_in[1];
    const float* edge_emb    = (const float*)d_in[2];
    const int*   mask        = (const int*)  d_in[3];
    const float* W1 = (const float*)d_in[4];
    const float* b1 = (const float*)d_in[5];
    const float* W2 = (const float*)d_in[6];
    const float* b2 = (const float*)d_in[7];
    const float* W3 = (const float*)d_in[8];
    const float* b3 = (const float*)d_in[9];
    char* ws = (char*)d_ws;

    prep_kernel<<<48 + 1152, 256, 0, stream>>>(W1, W2, op_emb, machine_emb, b1, ws);
    main_kernel<<<Bb * Nn, 256, 0, stream>>>(edge_emb, mask, b2, W3, b3, ws);
    lsm_apply_kernel<<<256, 256, 0, stream>>>(ws, (float*)d_out);
}

// Round 11
// 228.110 us; speedup vs baseline: 1.0400x; 1.0400x over previous
//
#include <hip/hip_runtime.h>
#include <math.h>

#define Bb 8
#define Nn 512
#define Mm 64
#define Dd 128
#define Hh 64
#define Gg 8                 // n's per block; grid = 4096/8 = 512 = 2 blocks/CU
#define NEG_BIG (-1.0e30f)

// per-wave edge buffer: 8 segments of 1KB, each padded +16B -> 260 floats
#define SEGF 260
#define BUFF (8 * SEGF)      // 2080 floats per buffer

typedef __bf16 bf16x8 __attribute__((ext_vector_type(8)));
typedef float  f32x4  __attribute__((ext_vector_type(4)));

// ws byte offsets (16B-aligned)
#define WS_WEB   0u          // 16384 B  bf16 We B-frags, frag-linear [16 frag][64 lane][8]
#define WS_W2B   16384u      // 8192 B   bf16 W2 B-frags, frag-linear [8 frag][64 lane][8]
#define WS_CWSF  24576u      // 131072 B fp32 CwsF[b][w][t][lane][r] (b1 folded, frag-swizzled)
#define WS_AOP   155648u     // 1048576 B fp32 Aop[b*N+n][h]
#define WS_SCORE 1204224u    // 1048576 B fp32 scores[b*N+n][m]
#define WS_PART  2252800u    // 4096 B   fp32 (max,sumexp) per block [512][2]

// async global->LDS DMA, 16B/lane; offset must be an ICE -> fold into gp, pass 0
#define GLOAD_LDS(gp, lp) __builtin_amdgcn_global_load_lds( \
    (const __attribute__((address_space(1))) void*)(gp),    \
    (__attribute__((address_space(3))) void*)(lp), 16, 0, 0)

// ---------- prep: weight B-frags + projections (CwsF frag-swizzled) ----------
__global__ __launch_bounds__(256) void prep_kernel(
    const float* __restrict__ W1, const float* __restrict__ W2,
    const float* __restrict__ op_emb, const float* __restrict__ machine_emb,
    const float* __restrict__ b1, char* __restrict__ ws)
{
    if (blockIdx.x < 48) {               // weight fragment prep
        __bf16* WeB = (__bf16*)(ws + WS_WEB);
        __bf16* W2B = (__bf16*)(ws + WS_W2B);
        int idx = blockIdx.x * 256 + threadIdx.x;
        if (idx < 8192) {                // We: 16 frags (t 0..3, ks 0..3)
            int fid = idx >> 9, rem = idx & 511;
            int lane = rem >> 3, j = rem & 7;
            int t = fid >> 2, ks = fid & 3;
            int q = lane >> 4, ln = lane & 15;
            int d = ks * 32 + q * 8 + j;
            int h = t * 16 + ln;
            WeB[idx] = (__bf16)W1[(size_t)(2 * Dd + d) * Hh + h];
        } else {                         // W2: 8 frags (t 0..3, ks 0..1)
            int i2 = idx - 8192;
            int fid = i2 >> 9, rem = i2 & 511;
            int lane = rem >> 3, j = rem & 7;
            int t = fid >> 1, ks = fid & 1;
            int q = lane >> 4, ln = lane & 15;
            int k = ks * 32 + q * 8 + j;
            int h = t * 16 + ln;
            W2B[i2] = (__bf16)W2[(size_t)k * Hh + h];
        }
        return;
    }
    // projections: 1152 blocks x 4 rows (B*M + B*N = 4608 rows of 64)
    float* CwsF = (float*)(ws + WS_CWSF);
    float* Aop  = (float*)(ws + WS_AOP);
    const int bid = (blockIdx.x - 48) * 4 + (threadIdx.x >> 6);
    const int h = threadIdx.x & 63;
    if (bid < Bb * Mm) {
        const float* mg = machine_emb + (size_t)bid * Dd;
        const float* Wm = W1 + (size_t)Dd * Hh;
        float acc = b1[h];
#pragma unroll 8
        for (int d = 0; d < Dd; ++d) acc = fmaf(mg[d], Wm[d * Hh + h], acc);
        // scatter into fragment order: [b][w][t][lane=q*16+ln][r]
        int b = bid >> 6, m = bid & 63;
        int wq = m >> 4, q = (m >> 2) & 3, r = m & 3;
        int t = h >> 4, ln = h & 15;
        CwsF[((((b * 4 + wq) * 4 + t) * 64) + (q * 16 + ln)) * 4 + r] = acc;
    } else {
        const int bn = bid - Bb * Mm;
        const float* og = op_emb + (size_t)bn * Dd;
        float acc = 0.f;
#pragma unroll 8
        for (int d = 0; d < Dd; ++d) acc = fmaf(og[d], W1[d * Hh + h], acc);
        Aop[(size_t)bn * Hh + h] = acc;
    }
}

// ---------- main: contiguous per-wave DMA slabs, padded LDS, fused partials ----------
__global__ __launch_bounds__(256, 2) void main_kernel(
    const float* __restrict__ edge_emb, const int* __restrict__ mask,
    const float* __restrict__ b2, const float* __restrict__ W3,
    const float* __restrict__ b3, char* __restrict__ ws)
{
    __shared__ float  sEdge[4 * 2 * BUFF];  // 66560 B: [wave][buf][seg][260 floats]
    __shared__ float  sAop[Gg * Hh];        //  2048 B
    __shared__ int    sMask[Gg * Mm];       //  2048 B
    __shared__ __bf16 sH1[Mm * 72];         //  9216 B
    __shared__ float  sRed[8];              //    32 B  -> 79.9 KB, 2 blocks/CU

    float* scores = (float*)(ws + WS_SCORE);
    float* part   = (float*)(ws + WS_PART);

    const int tid  = threadIdx.x;
    const int lane = tid & 63;
    const int w    = tid >> 6;
    const int q    = lane >> 4;
    const int ln   = lane & 15;
    const int bn0  = blockIdx.x * Gg;
    const int b    = bn0 >> 9;              // 64 blocks per batch; never straddles
    const int wu   = __builtin_amdgcn_readfirstlane(w);   // SGPR wave id for LDS bases

    // wave w's A-rows are the contiguous 8KB slab [w*2048, (w+1)*2048) floats of each tile.
    // Fully linear DMA: segment s = 1KB at +s*256 floats; lane contributes lane*16B.
    const float* ebase = edge_emb + (size_t)bn0 * (Mm * Dd) + w * 2048 + lane * 4;

    // ---- prologue DMAs: tiles g=0 -> buf0, g=1 -> buf1 (8 contiguous segs each) ----
    {
        float* d0 = &sEdge[(wu * 2 + 0) * BUFF];
        float* d1 = &sEdge[(wu * 2 + 1) * BUFF];
#pragma unroll
        for (int s = 0; s < 8; ++s) GLOAD_LDS(ebase + s * 256, d0 + s * SEGF);
#pragma unroll
        for (int s = 0; s < 8; ++s) GLOAD_LDS(ebase + 8192 + s * 256, d1 + s * SEGF);
    }

    // ---- one-time staging (linear/coalesced) ----
    if (tid < 128) {
        ((f32x4*)sAop)[tid] = ((const f32x4*)(ws + WS_AOP))[(size_t)bn0 * 16 + tid];
        ((int4*)sMask)[tid] = ((const int4*)mask)[(size_t)bn0 * 16 + tid];
    }

    // ---- weights + Cws tile into registers (held whole kernel) ----
    bf16x8 weF[16], w2F[8];
    f32x4  cv[4];
    {
        const bf16x8* WeB = (const bf16x8*)(ws + WS_WEB);
        const bf16x8* W2B = (const bf16x8*)(ws + WS_W2B);
#pragma unroll
        for (int f = 0; f < 16; ++f) weF[f] = WeB[f * 64 + lane];
#pragma unroll
        for (int f = 0; f < 8; ++f)  w2F[f] = W2B[f * 64 + lane];
        const f32x4* CwsF = (const f32x4*)(ws + WS_CWSF) + (size_t)b * 1024;
#pragma unroll
        for (int t = 0; t < 4; ++t)  cv[t] = CwsF[(w * 4 + t) * 64 + lane];
    }

    float b2v[4], w3v[4];
#pragma unroll
    for (int t = 0; t < 4; ++t) { b2v[t] = b2[t * 16 + ln]; w3v[t] = W3[t * 16 + ln]; }
    const float bias3 = b3[0];

    // A-frag LDS read offset for this lane: row ln -> seg ln>>1, half ln&1;
    // bank start = 4*(ln>>1) + 8*q mod 32 -> uniform 8 lanes per 4-bank group.
    const int rdoff = (ln >> 1) * SEGF + (ln & 1) * 128 + q * 8;

    float m_loc = NEG_BIG, l_loc = 0.f;     // per-lane online softmax state

    __syncthreads();   // staging visible (drains prologue DMAs too)

#pragma unroll
    for (int g = 0; g < Gg; ++g) {
        const int buf = g & 1;
        const float* ldsrd = &sEdge[(wu * 2 + buf) * BUFF];

        // drain only the tile being consumed; keep in-flight refill pending
        if (g == Gg - 1) __builtin_amdgcn_s_waitcnt(0x0F70);  // vmcnt(0) at tail
        else             __builtin_amdgcn_s_waitcnt(0x0F78);  // vmcnt(8)

        f32x4 lo[4], hi[4];
#pragma unroll
        for (int ks = 0; ks < 4; ++ks) {
            lo[ks] = *(const f32x4*)&ldsrd[rdoff + ks * 32];
            hi[ks] = *(const f32x4*)&ldsrd[rdoff + ks * 32 + 4];
        }
        bf16x8 af[4];
#pragma unroll
        for (int ks = 0; ks < 4; ++ks) {
            bf16x8 a;
            a[0] = (__bf16)lo[ks][0]; a[1] = (__bf16)lo[ks][1];
            a[2] = (__bf16)lo[ks][2]; a[3] = (__bf16)lo[ks][3];
            a[4] = (__bf16)hi[ks][0]; a[5] = (__bf16)hi[ks][1];
            a[6] = (__bf16)hi[ks][2]; a[7] = (__bf16)hi[ks][3];
            af[ks] = a;
        }

        // refill this buffer with tile g+2 (contiguous slab)
        if (g + 2 < Gg) {
            float* dst = &sEdge[(wu * 2 + buf) * BUFF];
            const float* src = ebase + (size_t)(g + 2) * 8192;
#pragma unroll
            for (int s = 0; s < 8; ++s) GLOAD_LDS(src + s * 256, dst + s * SEGF);
        }

        // acc init = Aop[n,h] + Cws[m,h]
        f32x4 acc[4];
#pragma unroll
        for (int t = 0; t < 4; ++t) {
            float av = sAop[g * Hh + t * 16 + ln];
            acc[t][0] = cv[t][0] + av; acc[t][1] = cv[t][1] + av;
            acc[t][2] = cv[t][2] + av; acc[t][3] = cv[t][3] + av;
        }

        // GEMM1: D = edge . We + (A+C)
#pragma unroll
        for (int t = 0; t < 4; ++t)
#pragma unroll
            for (int ks = 0; ks < 4; ++ks)
                acc[t] = __builtin_amdgcn_mfma_f32_16x16x32_bf16(af[ks], weF[t * 4 + ks], acc[t], 0, 0, 0);

        // epilogue 1: relu -> sH1 (wave-private rows, no barrier)
#pragma unroll
        for (int t = 0; t < 4; ++t)
#pragma unroll
            for (int r = 0; r < 4; ++r)
                sH1[(w * 16 + q * 4 + r) * 72 + t * 16 + ln] =
                    (__bf16)fmaxf(acc[t][r], 0.f);

        // GEMM2
        bf16x8 a2[2];
#pragma unroll
        for (int ks = 0; ks < 2; ++ks)
            a2[ks] = *(const bf16x8*)&sH1[(w * 16 + ln) * 72 + ks * 32 + q * 8];
        f32x4 c2[4];
#pragma unroll
        for (int t = 0; t < 4; ++t) c2[t] = (f32x4){0.f, 0.f, 0.f, 0.f};
#pragma unroll
        for (int t = 0; t < 4; ++t)
#pragma unroll
            for (int ks = 0; ks < 2; ++ks)
                c2[t] = __builtin_amdgcn_mfma_f32_16x16x32_bf16(a2[ks], w2F[t * 2 + ks], c2[t], 0, 0, 0);

        // epilogue 2: masked scores + online softmax partials
        float p[4] = {0.f, 0.f, 0.f, 0.f};
#pragma unroll
        for (int t = 0; t < 4; ++t)
#pragma unroll
            for (int r = 0; r < 4; ++r)
                p[r] += fmaxf(c2[t][r] + b2v[t], 0.f) * w3v[t];
#pragma unroll
        for (int r = 0; r < 4; ++r) {
            p[r] += __shfl_xor(p[r], 1, 64);
            p[r] += __shfl_xor(p[r], 2, 64);
            p[r] += __shfl_xor(p[r], 4, 64);
            p[r] += __shfl_xor(p[r], 8, 64);
        }
        // after reduce, all 16 ln-lanes of a q-group hold identical p[0..3]
        const int m0 = w * 16 + q * 4;
        const int* mrow = &sMask[g * Mm + m0];
        float vv[4];
#pragma unroll
        for (int r = 0; r < 4; ++r) {
            float v = p[r] + bias3;
            vv[r] = mrow[r] ? v : NEG_BIG;
            if (mrow[r]) {                  // online update with valid entries only
                float mn = fmaxf(m_loc, v);
                l_loc = l_loc * expf(m_loc - mn) + expf(v - mn);
                m_loc = mn;
            }
        }
        if (ln == 0) {
            float4 o; o.x = vv[0]; o.y = vv[1]; o.z = vv[2]; o.w = vv[3];
            *(float4*)&scores[(size_t)(bn0 + g) * Mm + m0] = o;
        }
    }

    // ---- block softmax partial: combine q-groups (xor 16,32), then waves ----
#pragma unroll
    for (int off = 16; off <= 32; off <<= 1) {
        float mo = __shfl_xor(m_loc, off, 64);
        float lo2 = __shfl_xor(l_loc, off, 64);
        float mn = fmaxf(m_loc, mo);
        l_loc = l_loc * expf(m_loc - mn) + lo2 * expf(mo - mn);
        m_loc = mn;
    }
    if (lane == 0) { sRed[w * 2] = m_loc; sRed[w * 2 + 1] = l_loc; }
    __syncthreads();
    if (tid == 0) {
        float gm = sRed[0], gl = sRed[1];
#pragma unroll
        for (int k = 1; k < 4; ++k) {
            float mo = sRed[k * 2], lo2 = sRed[k * 2 + 1];
            float mn = fmaxf(gm, mo);
            gl = gl * expf(gm - mn) + lo2 * expf(mo - mn);
            gm = mn;
        }
        float2 o; o.x = gm; o.y = gl;
        *(float2*)&part[blockIdx.x * 2] = o;
    }
}

// ---------- log-softmax: combine 64 partials per batch inline, apply ----------
__global__ __launch_bounds__(256) void lsm_apply_kernel(
    const char* __restrict__ ws, float* __restrict__ out)
{
    const float4* s4 = (const float4*)(ws + WS_SCORE);
    const float* part = (const float*)(ws + WS_PART);
    __shared__ float sCC;
    const int tid = threadIdx.x;
    const int b = blockIdx.x >> 5;       // 32 blocks per batch
    if (tid < 64) {                      // inline combine of 64 partials
        float2 p = *(const float2*)&part[(b * 64 + tid) * 2];
        float gm = p.x;
#pragma unroll
        for (int off = 1; off < 64; off <<= 1) gm = fmaxf(gm, __shfl_xor(gm, off, 64));
        float l = p.y * expf(p.x - gm);
#pragma unroll
        for (int off = 1; off < 64; off <<= 1) l += __shfl_xor(l, off, 64);
        if (tid == 0) sCC = gm + logf(l);
    }
    __syncthreads();
    const float c = sCC;
    const int i = blockIdx.x * 256 + tid;    // 65536 float4s
    float4 v = s4[i];
    v.x -= c; v.y -= c; v.z -= c; v.w -= c;
    ((float4*)out)[i] = v;
}

extern "C" void kernel_launch(void* const* d_in, const int* in_sizes, int n_in,
                              void* d_out, int out_size, void* d_ws, size_t ws_size,
                              hipStream_t stream)
{
    const float* op_emb      = (const float*)d_in[0];
    const float* machine_emb = (const float*)d_in[1];
    const float* edge_emb    = (const float*)d_in[2];
    const int*   mask        = (const int*)  d_in[3];
    const float* W1 = (const float*)d_in[4];
    const float* b1 = (const float*)d_in[5];
    const float* W2 = (const float*)d_in[6];
    const float* b2 = (const float*)d_in[7];
    const float* W3 = (const float*)d_in[8];
    const float* b3 = (const float*)d_in[9];
    char* ws = (char*)d_ws;

    prep_kernel<<<48 + 1152, 256, 0, stream>>>(W1, W2, op_emb, machine_emb, b1, ws);
    main_kernel<<<(Bb * Nn) / Gg, 256, 0, stream>>>(edge_emb, mask, b2, W3, b3, ws);
    lsm_apply_kernel<<<256, 256, 0, stream>>>(ws, (float*)d_out);
}